// Round 1
// 439.887 us; speedup vs baseline: 1.2275x; 1.2275x over previous
//
#include <hip/hip_runtime.h>
#include <hip/hip_bf16.h>
#include <math.h>

// Problem constants: B*H=16, N=16384, D=64, M=266 (padded to 272 = 17 tiles of 16)
#define BHN 16
#define NN 16384
#define DD 64
#define MM 266
#define MP 272          // padded M (17 MFMA tiles)
#define CTS 288         // ctxT / kc row stride

constexpr float DN    = 0.35355339059327373f;   // 64^-0.25
constexpr float HDN2  = 0.0625f;                // 0.5 * DN^2
constexpr float RATIO = 0.0613139339f;          // 266^-0.5
constexpr float EPSF  = 1e-4f;

// ws layout (float offsets)
#define WS_STAB 0                         // [16] k-stab (DN * max dash)
#define WS_PART 16                        // [16][64] per-block max partials (32 used)
#define WS_KC   1040                      // [16][288] final kc
#define WS_KCS  5648                      // [4][16][288] slices (raw, unscaled)
#define WS_CTXS 24080                     // [4][16][272][64] slices (raw, unscaled)
#define CTX_SLICE (BHN * MP * DD)         // 278528
#define KC_SLICE  (BHN * CTS)             // 4608
#define WS_VD   1138192                   // [16][64] sum_n v  (zeroed)
#define WS_CD   1139216                   // [16][64] sum_m ctx
#define WS_KSUM 1140240                   // [16]     sum_m kc
#define WS_PBH  1140256                   // pbh ushort[17408] (=8704 floats), pbl follows
#define WS_CTH  1157664                   // cth ushort[16*64*288], ctl follows
#define ZERO_OFF 5648
#define ZERO_CNT 1133568                  // KCS + CTXS + VD

typedef __attribute__((ext_vector_type(8))) short s16x8;   // 8 bf16 (4 VGPRs)
typedef __attribute__((ext_vector_type(4))) float f32x4;

#define MFMA(acc, a, b) acc = __builtin_amdgcn_mfma_f32_16x16x32_bf16(a, b, acc, 0, 0, 0)

__device__ __forceinline__ float bf2f_u(unsigned short h) {
  union { unsigned u; float f; } v; v.u = ((unsigned)h) << 16; return v.f;
}
// pack 2 floats -> 2 bf16 (RNE) via v_cvt_pk_bf16_f32; low16 = a, high16 = b
__device__ __forceinline__ unsigned pk_bf16(float a, float b) {
  float2 f; f.x = a; f.y = b;
  __hip_bfloat162 h = __float22bfloat162_rn(f);
  union { __hip_bfloat162 h; unsigned u; } c; c.h = h;
  return c.u;
}
// 8 floats -> bf16 hi + lo fragments
__device__ __forceinline__ void split8(const float* v, s16x8& hi, s16x8& lo) {
  union U { s16x8 s; unsigned u[4]; } H, L;
#pragma unroll
  for (int i = 0; i < 4; i++) {
    float a = v[2 * i], b = v[2 * i + 1];
    unsigned uh = pk_bf16(a, b);
    H.u[i] = uh;
    float r0 = a - bf2f_u((unsigned short)(uh & 0xffffu));
    float r1 = b - bf2f_u((unsigned short)(uh >> 16));
    L.u[i] = pk_bf16(r0, r1);
  }
  hi = H.s; lo = L.s;
}
__device__ __forceinline__ void split8g(const float* __restrict__ p,
                                        s16x8& hi, s16x8& lo, float& ss) {
  float4 f0 = *(const float4*)p;
  float4 f1 = *(const float4*)(p + 4);
  float v[8] = {f0.x, f0.y, f0.z, f0.w, f1.x, f1.y, f1.z, f1.w};
#pragma unroll
  for (int i = 0; i < 8; i++) ss += v[i] * v[i];
  split8(v, hi, lo);
}
__device__ __forceinline__ void split8l(const float* p, s16x8& hi, s16x8& lo) {
  float4 f0 = *(const float4*)p;
  float4 f1 = *(const float4*)(p + 4);
  float v[8] = {f0.x, f0.y, f0.z, f0.w, f1.x, f1.y, f1.z, f1.w};
  split8(v, hi, lo);
}

// ---------------- prep: proj -> bf16 hi/lo [272][64], pads zero ----------------
__global__ void prep_kernel(const float* __restrict__ P,
                            unsigned short* __restrict__ pbh,
                            unsigned short* __restrict__ pbl) {
  int idx = blockIdx.x * 256 + threadIdx.x;
  if (idx < MP * DD) {
    float f = (idx < MM * DD) ? P[idx] : 0.f;
    unsigned short h = (unsigned short)(pk_bf16(f, 0.f) & 0xffffu);
    pbh[idx] = h;
    pbl[idx] = (unsigned short)(pk_bf16(f - bf2f_u(h), 0.f) & 0xffffu);
  }
}

// ---------------- ctx: u = exp(dash-diag) UNstabilized; ctx' += u^T.v; kc' += sum u;
//                  also tracks max(dash) per block and sum_n v (fused kmax elimination)
__global__ __launch_bounds__(256) void ctx_kernel(
    const float* __restrict__ K, const float* __restrict__ V,
    const unsigned short* __restrict__ pbh, const unsigned short* __restrict__ pbl,
    float* __restrict__ ws) {
  __shared__ float vT[64 * 36];      // v chunk transposed [d][n]
  __shared__ float kpb[MP * 36];     // kp chunk transposed-ish [m-row][n]
  __shared__ float redm[4];
  const int tid = threadIdx.x;
  const int wave = tid >> 6, lane = tid & 63;
  const int l15 = lane & 15, quad = lane >> 4;
  const int bh = blockIdx.x;
  const int slice = blockIdx.y & 3;
  float* ctxs = ws + WS_CTXS + (size_t)slice * CTX_SLICE;
  float* kcs  = ws + WS_KCS + slice * KC_SLICE;
  f32x4 zero4 = {0.f, 0.f, 0.f, 0.f};
  f32x4 acc[5][4];
#pragma unroll
  for (int i = 0; i < 5; i++)
#pragma unroll
    for (int j = 0; j < 4; j++) acc[i][j] = zero4;
  float kcp[5] = {0.f, 0.f, 0.f, 0.f, 0.f};
  float vsum[8] = {0.f, 0.f, 0.f, 0.f, 0.f, 0.f, 0.f, 0.f};
  float mxk = -1e30f;

  for (int it = 0; it < 16; it++) {
    const int n0 = blockIdx.y * 512 + it * 32;
    // stage vT: conflict-free transposed write (n varies across lanes, d uniform)
#pragma unroll
    for (int j = 0; j < 2; j++) {
      const int n = tid & 31;
      const int d4 = ((tid >> 5) + j * 8) * 4;
      float4 vv = *(const float4*)(V + ((size_t)(bh * NN + n0 + n)) * DD + d4);
      vT[(d4 + 0) * 36 + n] = vv.x;
      vT[(d4 + 1) * 36 + n] = vv.y;
      vT[(d4 + 2) * 36 + n] = vv.z;
      vT[(d4 + 3) * 36 + n] = vv.w;
      vsum[j * 4 + 0] += vv.x;
      vsum[j * 4 + 1] += vv.y;
      vsum[j * 4 + 2] += vv.z;
      vsum[j * 4 + 3] += vv.w;
    }
    // kp for this wave's m-tiles over both 16-row groups
    s16x8 ah[2][2], al[2][2];
    float dg[2][4];
#pragma unroll
    for (int g = 0; g < 2; g++) {
      float ss = 0.f;
#pragma unroll
      for (int s = 0; s < 2; s++)
        split8g(K + ((size_t)(bh * NN + n0 + g * 16 + l15)) * DD + s * 32 + quad * 8,
                ah[g][s], al[g][s], ss);
      ss += __shfl_xor(ss, 16);
      ss += __shfl_xor(ss, 32);
#pragma unroll
      for (int r = 0; r < 4; r++) dg[g][r] = HDN2 * __shfl(ss, quad * 4 + r);
    }
#pragma unroll 5
    for (int ti = 0; ti < 5; ti++) {
      const int t = wave + ti * 4;
      if (t < 17) {
        f32x4 dd[2] = {zero4, zero4};
#pragma unroll
        for (int s = 0; s < 2; s++) {
          s16x8 b8h = *(const s16x8*)(pbh + (t * 16 + l15) * DD + s * 32 + quad * 8);
          s16x8 b8l = *(const s16x8*)(pbl + (t * 16 + l15) * DD + s * 32 + quad * 8);
#pragma unroll
          for (int g = 0; g < 2; g++) {
            MFMA(dd[g], ah[g][s], b8h); MFMA(dd[g], al[g][s], b8h); MFMA(dd[g], ah[g][s], b8l);
          }
        }
        const bool pad = (t == 16 && l15 >= 10);
#pragma unroll
        for (int g = 0; g < 2; g++) {
          float4 kp;
          float* kpp = (float*)&kp;
#pragma unroll
          for (int r = 0; r < 4; r++) {
            kpp[r] = __expf(DN * dd[g][r] - dg[g][r]);   // NO stab, NO ratio, NO eps
            if (!pad) mxk = fmaxf(mxk, dd[g][r]);
          }
          if (pad) { kp.x = kp.y = kp.z = kp.w = 0.f; }
          kcp[ti] += kpp[0] + kpp[1] + kpp[2] + kpp[3];
          *(float4*)(kpb + (t * 16 + l15) * 36 + g * 16 + quad * 4) = kp;
        }
      }
    }
    __syncthreads();   // tile data ready
    s16x8 vbh[4], vbl[4];
#pragma unroll
    for (int dt = 0; dt < 4; dt++)
      split8l(vT + (dt * 16 + l15) * 36 + quad * 8, vbh[dt], vbl[dt]);
#pragma unroll 5
    for (int ti = 0; ti < 5; ti++) {
      const int t = wave + ti * 4;
      if (t < 17) {
        s16x8 kah, kal;
        split8l(kpb + (t * 16 + l15) * 36 + quad * 8, kah, kal);
#pragma unroll
        for (int dt = 0; dt < 4; dt++) {
          MFMA(acc[ti][dt], kah, vbh[dt]);
          MFMA(acc[ti][dt], kal, vbh[dt]);
          MFMA(acc[ti][dt], kah, vbl[dt]);
        }
      }
    }
    __syncthreads();   // readers done before next chunk overwrites
  }
  // epilogue: slice atomics (8-way contention)
#pragma unroll 5
  for (int ti = 0; ti < 5; ti++) {
    const int t = wave + ti * 4;
    if (t < 17) {
      float kc = kcp[ti];
      kc += __shfl_xor(kc, 16);
      kc += __shfl_xor(kc, 32);
      if (lane < 16) atomicAdd(&kcs[bh * CTS + t * 16 + lane], kc);
#pragma unroll
      for (int dt = 0; dt < 4; dt++)
#pragma unroll
        for (int r = 0; r < 4; r++) {
          int m = t * 16 + quad * 4 + r;
          atomicAdd(&ctxs[((size_t)(bh * MP + m)) * DD + dt * 16 + l15], acc[ti][dt][r]);
        }
    }
  }
  // v column-sums: reduce over the 32-lane n-groups, one atomic per (group, d)
#pragma unroll
  for (int j = 0; j < 2; j++)
#pragma unroll
    for (int c = 0; c < 4; c++) {
      float s = vsum[j * 4 + c];
      s += __shfl_xor(s, 1);  s += __shfl_xor(s, 2);  s += __shfl_xor(s, 4);
      s += __shfl_xor(s, 8);  s += __shfl_xor(s, 16);
      if ((tid & 31) == 0)
        atomicAdd(&ws[WS_VD + bh * 64 + ((tid >> 5) + j * 8) * 4 + c], s);
    }
  // block max of raw dash (dd units) -> partial slot
#pragma unroll
  for (int d = 1; d < 64; d <<= 1) mxk = fmaxf(mxk, __shfl_xor(mxk, d));
  if (lane == 0) redm[wave] = mxk;
  __syncthreads();
  if (tid == 0)
    ws[WS_PART + bh * 64 + blockIdx.y] =
        fmaxf(fmaxf(redm[0], redm[1]), fmaxf(redm[2], redm[3]));
}

// ---------------- stab: reduce 32 partials ----------------
__global__ void stab_kernel(float* __restrict__ ws) {
  const int bh = blockIdx.x, lane = threadIdx.x;
  float m = (lane < 32) ? ws[WS_PART + bh * 64 + lane] : -1e30f;
#pragma unroll
  for (int d = 1; d < 64; d <<= 1) m = fmaxf(m, __shfl_xor(m, d));
  if (lane == 0) ws[WS_STAB + bh] = DN * m;
}

// ---------------- ctxt: reduce slices; apply ratio*e^{-stab} + ratio*EPS*sum_v;
//                  ctx -> bf16 hi/lo transposed; kc final ----------------
__global__ __launch_bounds__(256) void ctxt_kernel(
    float* __restrict__ ws, unsigned short* __restrict__ cth,
    unsigned short* __restrict__ ctl) {
  const int bh = blockIdx.x;
  const int idx = blockIdx.y * 256 + threadIdx.x;   // < 64*288
  const int d = idx / CTS, m = idx % CTS;
  const float stab = ws[WS_STAB + bh];
  const float scale = RATIO * __expf(-stab);
  const float reps  = RATIO * EPSF;
  float f = 0.f;
  if (m < MP) {
#pragma unroll
    for (int s = 0; s < 4; s++)
      f += ws[WS_CTXS + (size_t)s * CTX_SLICE + ((size_t)(bh * MP + m)) * DD + d];
  }
  float ctxf = (m < MM) ? (scale * f + reps * ws[WS_VD + bh * 64 + d]) : 0.f;
  unsigned short h = (unsigned short)(pk_bf16(ctxf, 0.f) & 0xffffu);
  cth[((size_t)(bh * DD) + d) * CTS + m] = h;
  ctl[((size_t)(bh * DD) + d) * CTS + m] =
      (unsigned short)(pk_bf16(ctxf - bf2f_u(h), 0.f) & 0xffffu);
  if (d == 0) {
    float kc = 0.f;
    if (m < MM) {
      float kr = 0.f;
#pragma unroll
      for (int s = 0; s < 4; s++) kr += ws[WS_KCS + s * KC_SLICE + bh * CTS + m];
      kc = scale * kr + reps * (float)NN;
    }
    ws[WS_KC + bh * CTS + m] = kc;
  }
}

// ---------------- csum: C_d = sum_m ctx[m][d]; Kc = sum_m kc[m] ----------------
__global__ __launch_bounds__(256) void csum_kernel(
    const unsigned short* __restrict__ cth, const unsigned short* __restrict__ ctl,
    float* __restrict__ ws) {
  const int bh = blockIdx.x, t = threadIdx.x;
  const int d = t >> 2, p = t & 3;
  const unsigned short* rh = cth + ((size_t)(bh * DD) + d) * CTS;
  const unsigned short* rl = ctl + ((size_t)(bh * DD) + d) * CTS;
  float s = 0.f;
  for (int i = 0; i < 68; i++) {
    int m = p * 68 + i;            // covers 0..271, pads are exact zeros
    s += bf2f_u(rh[m]) + bf2f_u(rl[m]);
  }
  s += __shfl_xor(s, 1);
  s += __shfl_xor(s, 2);
  if (p == 0) ws[WS_CD + bh * 64 + d] = s;
  if (t < 64) {
    float kk = 0.f;
    for (int m = t; m < MM; m += 64) kk += ws[WS_KC + bh * CTS + m];
#pragma unroll
    for (int dd2 = 1; dd2 < 64; dd2 <<= 1) kk += __shfl_xor(kk, dd2);
    if (t == 0) ws[WS_KSUM + bh] = kk;
  }
}

// ---------------- out: SINGLE pass — w = exp(dash-diag) unstabilized, row max
//                  tracked alongside; EPS terms applied analytically at the end.
//                  out = (sum_m w*ctx + EPS*e^{s_r}*C_d) / (sum_m w*kc + EPS*e^{s_r}*Kc)
__global__ __launch_bounds__(256) void out_kernel(
    const float* __restrict__ Q, const unsigned short* __restrict__ pbh,
    const unsigned short* __restrict__ pbl, const unsigned short* __restrict__ cth,
    const unsigned short* __restrict__ ctl, const float* __restrict__ ws,
    float* __restrict__ Out) {
  __shared__ float qpb[4][2][16 * 36];   // per-wave, per-group bounce (18.4 KB)
  const int tid = threadIdx.x;
  const int wave = tid >> 6, lane = tid & 63;
  const int l15 = lane & 15, quad = lane >> 4;
  const int bh = blockIdx.x;
  const int n0 = blockIdx.y * 128 + wave * 32;
  f32x4 zero4 = {0.f, 0.f, 0.f, 0.f};
  s16x8 ah[2][2], al[2][2];
  float sub[2][4];                       // diag only (no stab here)
#pragma unroll
  for (int g = 0; g < 2; g++) {
    float ss = 0.f;
#pragma unroll
    for (int s = 0; s < 2; s++)
      split8g(Q + ((size_t)(bh * NN + n0 + g * 16 + l15)) * DD + s * 32 + quad * 8,
              ah[g][s], al[g][s], ss);
    ss += __shfl_xor(ss, 16);
    ss += __shfl_xor(ss, 32);
#pragma unroll
    for (int r = 0; r < 4; r++) sub[g][r] = HDN2 * __shfl(ss, quad * 4 + r);
  }
  f32x4 oa[2][4];
#pragma unroll
  for (int g = 0; g < 2; g++)
#pragma unroll
    for (int dt = 0; dt < 4; dt++) oa[g][dt] = zero4;
  float dn[2][4] = {{0.f,0.f,0.f,0.f},{0.f,0.f,0.f,0.f}};
  float mx[2][4] = {{-1e30f,-1e30f,-1e30f,-1e30f},{-1e30f,-1e30f,-1e30f,-1e30f}};
  for (int s9 = 0; s9 < 9; s9++) {
#pragma unroll
    for (int u = 0; u < 2; u++) {
      const int t = s9 * 2 + u;
      if (t < 17) {
        f32x4 dd[2] = {zero4, zero4};
#pragma unroll
        for (int s = 0; s < 2; s++) {
          s16x8 b8h = *(const s16x8*)(pbh + (t * 16 + l15) * DD + s * 32 + quad * 8);
          s16x8 b8l = *(const s16x8*)(pbl + (t * 16 + l15) * DD + s * 32 + quad * 8);
#pragma unroll
          for (int g = 0; g < 2; g++) {
            MFMA(dd[g], ah[g][s], b8h); MFMA(dd[g], al[g][s], b8h); MFMA(dd[g], ah[g][s], b8l);
          }
        }
        const float kcv = ws[WS_KC + bh * CTS + t * 16 + l15];
        const bool pad = (t == 16 && l15 >= 10);
#pragma unroll
        for (int g = 0; g < 2; g++)
#pragma unroll
          for (int r = 0; r < 4; r++) {
            float dv = dd[g][r];
            if (!pad) mx[g][r] = fmaxf(mx[g][r], dv);
            float w = __expf(DN * dv - sub[g][r]);
            if (pad) w = 0.f;
            dn[g][r] += w * kcv;
            qpb[wave][g][(quad * 4 + r) * 36 + u * 16 + l15] = w;
          }
      } else {
#pragma unroll
        for (int g = 0; g < 2; g++)
#pragma unroll
          for (int r = 0; r < 4; r++) qpb[wave][g][(quad * 4 + r) * 36 + 16 + l15] = 0.f;
      }
    }
    s16x8 qah[2], qal[2];
#pragma unroll
    for (int g = 0; g < 2; g++)
      split8l(qpb[wave][g] + l15 * 36 + quad * 8, qah[g], qal[g]);  // wave-private: no barrier
#pragma unroll
    for (int dt = 0; dt < 4; dt++) {
      s16x8 c8h = *(const s16x8*)(cth + ((size_t)(bh * DD + dt * 16 + l15)) * CTS + s9 * 32 + quad * 8);
      s16x8 c8l = *(const s16x8*)(ctl + ((size_t)(bh * DD + dt * 16 + l15)) * CTS + s9 * 32 + quad * 8);
#pragma unroll
      for (int g = 0; g < 2; g++) {
        MFMA(oa[g][dt], qah[g], c8h);
        MFMA(oa[g][dt], qal[g], c8h);
        MFMA(oa[g][dt], qah[g], c8l);
      }
    }
  }
  const float kcsum = ws[WS_KSUM + bh];
  float er[2][4];
#pragma unroll
  for (int g = 0; g < 2; g++)
#pragma unroll
    for (int r = 0; r < 4; r++) {
#pragma unroll
      for (int d = 1; d < 16; d <<= 1) {
        dn[g][r] += __shfl_xor(dn[g][r], d);
        mx[g][r] = fmaxf(mx[g][r], __shfl_xor(mx[g][r], d));
      }
      float e = EPSF * __expf(DN * mx[g][r]);
      er[g][r] = e;
      dn[g][r] = 1.0f / (dn[g][r] + e * kcsum);
    }
#pragma unroll
  for (int g = 0; g < 2; g++)
#pragma unroll
    for (int dt = 0; dt < 4; dt++) {
      const float cdv = ws[WS_CD + bh * 64 + dt * 16 + l15];
#pragma unroll
      for (int r = 0; r < 4; r++)
        Out[((size_t)(bh * NN + n0 + g * 16 + quad * 4 + r)) * DD + dt * 16 + l15] =
            (oa[g][dt][r] + er[g][r] * cdv) * dn[g][r];
    }
}

extern "C" void kernel_launch(void* const* d_in, const int* in_sizes, int n_in,
                              void* d_out, int out_size, void* d_ws, size_t ws_size,
                              hipStream_t stream) {
  const float* q = (const float*)d_in[0];
  const float* k = (const float*)d_in[1];
  const float* v = (const float*)d_in[2];
  const float* p = (const float*)d_in[3];
  float* out = (float*)d_out;
  float* ws  = (float*)d_ws;
  unsigned short* pbh = (unsigned short*)(ws + WS_PBH);
  unsigned short* pbl = pbh + MP * DD;
  unsigned short* cth = (unsigned short*)(ws + WS_CTH);
  unsigned short* ctl = cth + (size_t)BHN * DD * CTS;

  hipMemsetAsync(ws + ZERO_OFF, 0, (size_t)ZERO_CNT * sizeof(float), stream);
  prep_kernel<<<68, 256, 0, stream>>>(p, pbh, pbl);
  ctx_kernel<<<dim3(BHN, 32), 256, 0, stream>>>(k, v, pbh, pbl, ws);
  stab_kernel<<<BHN, 64, 0, stream>>>(ws);
  ctxt_kernel<<<dim3(BHN, 72), 256, 0, stream>>>(ws, cth, ctl);
  csum_kernel<<<BHN, 256, 0, stream>>>(cth, ctl, ws);
  out_kernel<<<dim3(BHN, 128), 256, 0, stream>>>(q, pbh, pbl, cth, ctl, ws, out);
}